// Round 6
// baseline (412.340 us; speedup 1.0000x reference)
//
#include <hip/hip_runtime.h>
#include <cstdint>
#include <cstddef>

typedef __bf16 bf16_t;
typedef __bf16 bf16x8 __attribute__((ext_vector_type(8)));
typedef __bf16 bf16x4 __attribute__((ext_vector_type(4)));
typedef float floatx4 __attribute__((ext_vector_type(4)));
typedef float f32x16 __attribute__((ext_vector_type(16)));

#define B_  2
#define T_  2048
#define C_  2048
#define H_  16
#define HD_ 128

// 1/sqrt(128) * log2(e) — folded into Q at QKV-GEMM epilogue
#define K_ATTN_SCALE (0.08838834764831843f * 1.44269504088896f)

// ---- async global->LDS, 16B per lane (m97 recipe) ----
__device__ __forceinline__ void async_copy16(const void* g, void* l) {
  __builtin_amdgcn_global_load_lds((const __attribute__((address_space(1))) unsigned int*)g,
                                   (__attribute__((address_space(3))) unsigned int*)l,
                                   16, 0, 0);
}

#define BAR()     asm volatile("s_barrier" ::: "memory")
#define VMCNT(n)  asm volatile("s_waitcnt vmcnt(" #n ")" ::: "memory")

// ---------------- convert fp32 -> bf16 (flat) ----------------
__global__ __launch_bounds__(256) void cvt_f32_bf16(const float* __restrict__ in,
                                                    bf16_t* __restrict__ out, int n4) {
  int i = blockIdx.x * 256 + threadIdx.x;
  if (i >= n4) return;
  const float4 v = ((const float4*)in)[i];
  bf16x4 o;
  o[0] = (bf16_t)v.x; o[1] = (bf16_t)v.y; o[2] = (bf16_t)v.z; o[3] = (bf16_t)v.w;
  ((bf16x4*)out)[i] = o;
}

// ------- transpose + convert: W[Kd][Nd] fp32 -> Wt[Nd][Kd] bf16 -------
__global__ __launch_bounds__(256) void transpose_cvt(const float* __restrict__ W,
                                                     bf16_t* __restrict__ Wt,
                                                     int Kd, int Nd) {
  __shared__ float tile[32][33];
  const int tx = threadIdx.x, ty = threadIdx.y;
  const int n0 = blockIdx.x * 32, k0 = blockIdx.y * 32;
#pragma unroll
  for (int j = ty; j < 32; j += 8)
    tile[j][tx] = W[(size_t)(k0 + j) * Nd + n0 + tx];
  __syncthreads();
#pragma unroll
  for (int j = ty; j < 32; j += 8)
    Wt[(size_t)(n0 + j) * Kd + k0 + tx] = (bf16_t)tile[tx][j];
}

// =====================================================================
// QKV GEMM — 256x256 tile, 8 waves, BK=64 as 2 k-slices of 32.
// Register fragment double-buffer; 2 barriers/tile; counted vmcnt(8).
// (round-5 version, unchanged — fell out of top-5)
// =====================================================================
#define GBM 256
#define GBN 256
#define GBK 64

__global__ __launch_bounds__(512, 2) void gemm_qkv(
    const bf16_t* __restrict__ A, const bf16_t* __restrict__ Bt,
    const float* __restrict__ bias,
    bf16_t* __restrict__ Qo, bf16_t* __restrict__ Ko, bf16_t* __restrict__ Vo,
    int K) {
  __shared__ __align__(16) char smem[131072];
  const int tid = threadIdx.x;
  const int wave = tid >> 6, lane = tid & 63;
  const int quad = lane >> 4, l15 = lane & 15;
  const int wm = wave >> 2, wn = wave & 3;
  const int bm = blockIdx.y * GBM, bn = blockIdx.x * GBN;

  const bf16_t* asrc[2];
  const bf16_t* bsrc[2];
#pragma unroll
  for (int l = 0; l < 2; ++l) {
    int p = l * 8192 + tid * 16;
    int r = p >> 6;
    int c = ((p >> 4) & 3) ^ ((r >> 1) & 3);
    asrc[l] = A  + (size_t)(bm + r) * K + c * 8;
    bsrc[l] = Bt + (size_t)(bn + r) * K + c * 8;
  }

  auto stage = [&](int buf, int ks, int kofs) {
    char* Asl = smem + buf * 65536 + ks * 16384;
    char* Bsl = Asl + 32768;
#pragma unroll
    for (int l = 0; l < 2; ++l)
      async_copy16(asrc[l] + kofs, Asl + l * 8192 + tid * 16);
#pragma unroll
    for (int l = 0; l < 2; ++l)
      async_copy16(bsrc[l] + kofs, Bsl + l * 8192 + tid * 16);
  };

  const int sxr = ((l15 >> 1) & 3) << 4;
  const int cb  = (quad * 16) ^ sxr;
  const int arow = (wm * 128 + l15) * 64;
  const int brow = (wn * 64 + l15) * 64;

  floatx4 acc[8][4] = {};
  bf16x8 a0[4], a1[4], b0[4], b1[4];

  stage(0, 0, 0);
  stage(0, 1, 32);
  stage(1, 0, GBK);
  VMCNT(8);
  BAR();
  {
    const char* Ab = smem;
    const char* Bb = smem + 32768;
#pragma unroll
    for (int i = 0; i < 4; ++i)
      a0[i] = *(const bf16x8*)(Ab + arow + i * 1024 + cb);
#pragma unroll
    for (int j = 0; j < 4; ++j)
      b0[j] = *(const bf16x8*)(Bb + brow + j * 1024 + cb);
  }

  const int NT = K / GBK;
  for (int t = 0; t < NT; ++t) {
    const char* Ab  = smem + (t & 1) * 65536;
    const char* Bb  = Ab + 32768;
    const char* Abn = smem + ((t + 1) & 1) * 65536;
    const char* Bbn = Abn + 32768;

#pragma unroll
    for (int i = 0; i < 4; ++i)
      a1[i] = *(const bf16x8*)(Ab + arow + 4096 + i * 1024 + cb);
    if (t + 1 < NT) stage((t + 1) & 1, 1, (t + 1) * GBK + 32);
#pragma unroll
    for (int i = 0; i < 4; ++i)
#pragma unroll
      for (int j = 0; j < 4; ++j)
        acc[i][j] = __builtin_amdgcn_mfma_f32_16x16x32_bf16(a0[i], b0[j], acc[i][j], 0, 0, 0);
    if (t + 1 < NT) { VMCNT(8); } else { VMCNT(0); }
    BAR();

#pragma unroll
    for (int i = 0; i < 4; ++i)
      a0[i] = *(const bf16x8*)(Ab + 16384 + arow + i * 1024 + cb);
#pragma unroll
    for (int j = 0; j < 4; ++j)
      b1[j] = *(const bf16x8*)(Bb + 16384 + brow + j * 1024 + cb);
#pragma unroll
    for (int i = 0; i < 4; ++i)
#pragma unroll
      for (int j = 0; j < 4; ++j)
        acc[4 + i][j] = __builtin_amdgcn_mfma_f32_16x16x32_bf16(a1[i], b0[j], acc[4 + i][j], 0, 0, 0);

#pragma unroll
    for (int i = 0; i < 4; ++i)
      a1[i] = *(const bf16x8*)(Ab + 16384 + arow + 4096 + i * 1024 + cb);
    if (t + 2 < NT) stage(t & 1, 0, (t + 2) * GBK);
#pragma unroll
    for (int i = 0; i < 4; ++i)
#pragma unroll
      for (int j = 0; j < 4; ++j)
        acc[i][j] = __builtin_amdgcn_mfma_f32_16x16x32_bf16(a0[i], b1[j], acc[i][j], 0, 0, 0);
    if (t + 2 < NT)      { VMCNT(8); }
    else if (t + 1 < NT) { VMCNT(4); }
    else                 { VMCNT(0); }
    BAR();

    if (t + 1 < NT) {
#pragma unroll
      for (int i = 0; i < 4; ++i)
        a0[i] = *(const bf16x8*)(Abn + arow + i * 1024 + cb);
#pragma unroll
      for (int j = 0; j < 4; ++j)
        b0[j] = *(const bf16x8*)(Bbn + brow + j * 1024 + cb);
    }
#pragma unroll
    for (int i = 0; i < 4; ++i)
#pragma unroll
      for (int j = 0; j < 4; ++j)
        acc[4 + i][j] = __builtin_amdgcn_mfma_f32_16x16x32_bf16(a1[i], b1[j], acc[4 + i][j], 0, 0, 0);
  }

  float bias_r[4];
#pragma unroll
  for (int j = 0; j < 4; ++j)
    bias_r[j] = bias[bn + wn * 64 + j * 16 + l15];

  if (bn < 2 * C_) {
    const int which = bn >> 11;
    bf16_t* dst0 = which ? Ko : Qo;
    const float scl = which ? 1.0f : K_ATTN_SCALE;
#pragma unroll
    for (int i = 0; i < 8; ++i) {
      const int m = bm + wm * 128 + i * 16 + quad * 4;
      const int b = m >> 11, tq = m & 2047;
#pragma unroll
      for (int j = 0; j < 4; ++j) {
        const int n = bn + wn * 64 + j * 16 + l15;
        const int cc = n & 2047;
        const int h = cc >> 7, d = cc & 127;
        bf16_t* dst = dst0 + (((size_t)(b * H_ + h)) * T_ + tq) * HD_ + d;
#pragma unroll
        for (int r = 0; r < 4; ++r)
          dst[(size_t)r * HD_] = (bf16_t)((acc[i][j][r] + bias_r[j]) * scl);
      }
    }
  } else {
    __syncthreads();
    bf16_t* vt = (bf16_t*)smem;
#pragma unroll
    for (int i = 0; i < 8; ++i) {
      const int tl = wm * 128 + i * 16 + quad * 4;
#pragma unroll
      for (int j = 0; j < 4; ++j) {
        const int dl = wn * 64 + j * 16 + l15;
        const int sw = 8 * (dl & 15);
#pragma unroll
        for (int r = 0; r < 4; ++r)
          vt[dl * 256 + ((tl + r) ^ sw)] = (bf16_t)(acc[i][j][r] + bias_r[j]);
      }
    }
    __syncthreads();
    const int dr = tid >> 1, half = tid & 1;
    const int h = ((bn - 2 * C_) >> 7) + (dr >> 7);
    const int b = bm >> 11, t0g = bm & 2047;
    bf16_t* dst = Vo + ((size_t)(b * H_ + h) * HD_ + (dr & 127)) * T_ + t0g;
#pragma unroll
    for (int cc2 = 0; cc2 < 16; ++cc2) {
      const int c = half * 16 + cc2;
      uint4 v = *(const uint4*)&vt[dr * 256 + ((c ^ (dr & 15)) * 8)];
      *(uint4*)(dst + c * 8) = v;
    }
  }
}

// ---------------- proj GEMM (m97 structure + XOR-swizzled LDS, fp32 out) ----------------
#define TM 128
#define TN 128
#define BK 64

__global__ __launch_bounds__(256) void gemm_proj(
    const bf16_t* __restrict__ A, const bf16_t* __restrict__ Bt,
    const float* __restrict__ bias, float* __restrict__ Cout,
    int M, int N, int K) {
  __shared__ __align__(16) char smem[32768];
  bf16_t (*As)[BK] = (bf16_t(*)[BK])smem;
  bf16_t (*Bs)[BK] = (bf16_t(*)[BK])(smem + 16384);
  const int tid = threadIdx.x;
  const int wave = tid >> 6, lane = tid & 63;
  const int quad = lane >> 4, l15 = lane & 15;
  const int bm = blockIdx.y * TM, bn = blockIdx.x * TN;
  const int wm = (wave >> 1) * 64, wn = (wave & 1) * 64;
  const int sw = l15 & 7;

  floatx4 acc[4][4] = {};

  for (int k0 = 0; k0 < K; k0 += BK) {
#pragma unroll
    for (int it = 0; it < 4; ++it) {
      int p = it * 4096 + tid * 16;
      int r = p >> 7;
      int cg = ((p >> 4) & 7) ^ (r & 7);
      async_copy16(A + (size_t)(bm + r) * K + k0 + cg * 8, (char*)&As[0][0] + p);
      async_copy16(Bt + (size_t)(bn + r) * K + k0 + cg * 8, (char*)&Bs[0][0] + p);
    }
    __syncthreads();
#pragma unroll
    for (int kc = 0; kc < 2; ++kc) {
      const int cidx = (kc * 4 + quad) ^ sw;
      bf16x8 af[4], bf[4];
#pragma unroll
      for (int i = 0; i < 4; ++i)
        af[i] = *(const bf16x8*)&As[wm + i * 16 + l15][cidx * 8];
#pragma unroll
      for (int j = 0; j < 4; ++j)
        bf[j] = *(const bf16x8*)&Bs[wn + j * 16 + l15][cidx * 8];
#pragma unroll
      for (int i = 0; i < 4; ++i)
#pragma unroll
        for (int j = 0; j < 4; ++j)
          acc[i][j] = __builtin_amdgcn_mfma_f32_16x16x32_bf16(af[i], bf[j], acc[i][j], 0, 0, 0);
    }
    __syncthreads();
  }

#pragma unroll
  for (int i = 0; i < 4; ++i) {
#pragma unroll
    for (int j = 0; j < 4; ++j) {
#pragma unroll
      for (int r = 0; r < 4; ++r) {
        int m = bm + wm + i * 16 + quad * 4 + r;
        int n = bn + wn + j * 16 + l15;
        Cout[(size_t)m * N + n] = acc[i][j][r] + bias[n];
      }
    }
  }
}

// =====================================================================
// Causal flash attention — 32x32x16 MFMA, in-lane softmax (m214-style).
// Swapped QK^T: mfma(K,Q) -> lane&31 = q, 16 k-rows in regs; softmax is
// pure VALU (16 exp2 + row-sum) + one shfl_xor(32) for the partner half.
// P -> PV B-frag via cvt_pk pairs + v_permlane32_swap_b32 (no ds_bpermute).
// Wave (of 4) owns (qh=w&1, kh=w>>1): 32q x 32kv slot of each 64-chunk;
// every chunk = uniform 1 slot/wave (A) or 2 (A+B dual) — no idling.
// kh-split partial O/l combined at end through the dead K/V LDS.
// K/V staging + chunk-swizzles identical to verified prior version.
// =====================================================================
__global__ __launch_bounds__(256) void attn(const bf16_t* __restrict__ Q,
                                            const bf16_t* __restrict__ Kg,
                                            const bf16_t* __restrict__ Vt,
                                            bf16_t* __restrict__ O) {
  __shared__ __align__(16) char smem[66560];   // Ks 32K | Vs 32K | lbuf 1K
  const int tid = threadIdx.x;
  const int wave = tid >> 6, lane = tid & 63;
  const int hi = lane >> 5, l31 = lane & 31;
  const int qh = wave & 1, kh = wave >> 1;
  const int j = blockIdx.x;        // 0..15
  const int bh = blockIdx.y;
  const int b = bh >> 4, h = bh & 15;
  const int qtA = 31 - j, qtB = j;           // heavy, light
  const int nchA = qtA + 1, nchB = qtB + 1;

  const bf16_t* Qh = Q + (size_t)bh * T_ * HD_;
  const bf16_t* Kh = Kg + (size_t)bh * T_ * HD_;
  const bf16_t* Vh = Vt + (size_t)bh * HD_ * T_;

  float* xb32 = (float*)smem;                 // 32KB combine buffer (epilogue)
  float* lbuf = (float*)(smem + 65536);       // 512B l exchange

  // ---- staging (identical to prior verified version) ----
  auto stage = [&](int buf, int kt0) {
#pragma unroll
    for (int it = 0; it < 4; ++it) {
      int p = it * 4096 + tid * 16;
      int r = p >> 8;
      int cg = ((p >> 4) & 15) ^ (r & 15);
      async_copy16(Kh + (size_t)(kt0 + r) * HD_ + cg * 8, smem + buf * 16384 + p);
    }
#pragma unroll
    for (int it = 0; it < 4; ++it) {
      int p = it * 4096 + tid * 16;
      int r = p >> 7;
      int cg = ((p >> 4) & 7) ^ (r & 7);
      async_copy16(Vh + (size_t)r * T_ + kt0 + cg * 8, smem + 32768 + buf * 16384 + p);
    }
  };

  const int q0Arow = qtA * 64 + qh * 32;
  const int q0Brow = qtB * 64 + qh * 32;
  const bf16_t* qpA = Qh + (size_t)(q0Arow + l31) * HD_ + hi * 8;
  const bf16_t* qpB = Qh + (size_t)(q0Brow + l31) * HD_ + hi * 8;

  f32x16 oA[4] = {}, oB[4] = {};
  float l_A = 0.0f, l_B = 0.0f;

  const int swk = l31 & 15;   // K-row chunk swizzle (row&15 == l31&15)
  const int swv = l31 & 7;    // V-row chunk swizzle (row&7  == l31&7)
  const int krbase = (kh * 32 + l31) * 256;   // K LDS row byte base

  // one (qh,kh) slot: QK^T (2x4 chains) -> softmax -> pack/swap -> PV
  auto slot = [&](int buf, int kt0, const bf16_t* qp, f32x16 (&oacc)[4], float& l_i,
                  int qrow, bool mask) {
    const char* Kb = smem + buf * 16384;
    const char* Vb = smem + 32768 + buf * 16384;
    f32x16 s0 = {}, s1 = {};
#pragma unroll
    for (int m = 0; m < 4; ++m) {
      bf16x8 kf = *(const bf16x8*)(Kb + krbase + (((2 * m + hi) ^ swk) << 4));
      bf16x8 qf = *(const bf16x8*)(qp + m * 16);
      s0 = __builtin_amdgcn_mfma_f32_32x32x16_bf16(kf, qf, s0, 0, 0, 0);
    }
#pragma unroll
    for (int m = 4; m < 8; ++m) {
      bf16x8 kf = *(const bf16x8*)(Kb + krbase + (((2 * m + hi) ^ swk) << 4));
      bf16x8 qf = *(const bf16x8*)(qp + m * 16);
      s1 = __builtin_amdgcn_mfma_f32_32x32x16_bf16(kf, qf, s1, 0, 0, 0);
    }
    // softmax (no-max form, Q pre-scaled to log2 domain)
    const int qg = qrow + l31;
    float p[16];
    float ps = 0.0f;
#pragma unroll
    for (int r = 0; r < 16; ++r) {
      float v = s0[r] + s1[r];
      float e = __builtin_amdgcn_exp2f(v);
      if (mask) {
        int kt = kt0 + kh * 32 + (r & 3) + 8 * (r >> 2) + 4 * hi;
        e = (kt <= qg) ? e : 0.0f;
      }
      ps += e;
      p[r] = e;
    }
    ps += __shfl_xor(ps, 32);
    l_i += ps;
    // pack P to PV B-frags: k-window m2 covers reg groups 2*m2, 2*m2+1
    union PF { unsigned int w[4]; bf16x8 v; } pf[2];
#pragma unroll
    for (int m2 = 0; m2 < 2; ++m2) {
      union PK { bf16_t h[2]; unsigned int u; } a0, a1, c0, c1;
      const int ga = 8 * m2, gb = 8 * m2 + 4;
      a0.h[0] = (bf16_t)p[ga + 0]; a0.h[1] = (bf16_t)p[ga + 1];
      a1.h[0] = (bf16_t)p[ga + 2]; a1.h[1] = (bf16_t)p[ga + 3];
      c0.h[0] = (bf16_t)p[gb + 0]; c0.h[1] = (bf16_t)p[gb + 1];
      c1.h[0] = (bf16_t)p[gb + 2]; c1.h[1] = (bf16_t)p[gb + 3];
      unsigned int wa0 = a0.u, wa1 = a1.u, wb0 = c0.u, wb1 = c1.u;
      // swap: wa' = [wa_lo;wb_lo] (frag w0), wb' = [wa_hi;wb_hi] (frag w2)
      asm("v_permlane32_swap_b32 %0, %1" : "+v"(wa0), "+v"(wb0));
      asm("v_permlane32_swap_b32 %0, %1" : "+v"(wa1), "+v"(wb1));
      pf[m2].w[0] = wa0; pf[m2].w[1] = wa1; pf[m2].w[2] = wb0; pf[m2].w[3] = wb1;
    }
    // PV: O^T stripe — A = V^T rows (d), B = P
#pragma unroll
    for (int g = 0; g < 4; ++g) {
      const int vrb = (g * 32 + l31) * 128;
#pragma unroll
      for (int m2 = 0; m2 < 2; ++m2) {
        const int cc = kh * 4 + m2 * 2 + hi;
        bf16x8 vf = *(const bf16x8*)(Vb + vrb + ((cc ^ swv) << 4));
        oacc[g] = __builtin_amdgcn_mfma_f32_32x32x16_bf16(vf, pf[m2].v, oacc[g], 0, 0, 0);
      }
    }
  };

  stage(0, 0);
  for (int ch = 0; ch < nchA; ++ch) {
    __syncthreads();
    if (ch + 1 < nchA) stage((ch + 1) & 1, (ch + 1) * 64);  // fly during compute
    const int buf = ch & 1;
    slot(buf, ch * 64, qpA, oA, l_A, q0Arow, ch == nchA - 1);
    if (ch < nchB)
      slot(buf, ch * 64, qpB, oB, l_B, q0Brow, ch == nchB - 1);
  }

  // ---------------- epilogue: combine kh halves, write O ----------------
  auto dumpAcc = [&](f32x16 (&o)[4], float lp) {
#pragma unroll
    for (int g = 0; g < 4; ++g)
#pragma unroll
      for (int r = 0; r < 16; ++r)
        xb32[qh * 4096 + (g * 16 + r) * 64 + lane] = o[g][r];
    lbuf[qh * 64 + lane] = lp;
  };
  auto combineTile = [&](f32x16 (&o)[4], float lp) {
    const float inv = 1.0f / (lp + lbuf[qh * 64 + lane]);
    const int rr = qh * 32 + l31;
    char* ob = smem + 32768 + rr * 256;
#pragma unroll
    for (int g = 0; g < 4; ++g)
#pragma unroll
      for (int r1 = 0; r1 < 4; ++r1) {
        union { bf16_t hh[4]; uint2 u2; } w;
#pragma unroll
        for (int k = 0; k < 4; ++k)
          w.hh[k] = (bf16_t)((o[g][r1 * 4 + k] +
                              xb32[qh * 4096 + (g * 16 + r1 * 4 + k) * 64 + lane]) * inv);
        const int chunk = 4 * g + r1;
        *(uint2*)(ob + ((chunk ^ (rr & 15)) << 4) + 8 * hi) = w.u2;
      }
  };
  auto storeTile = [&](int qt) {
    const int row = tid >> 2, seg = tid & 3;
    bf16_t* Og = O + ((size_t)(b * T_ + qt * 64 + row)) * C_ + h * HD_;
    const char* sb = smem + 32768 + row * 256;
#pragma unroll
    for (int c4 = 0; c4 < 4; ++c4) {
      const int c = seg * 4 + c4;
      uint4 v = *(const uint4*)(sb + ((c ^ (row & 15)) << 4));
      *(uint4*)(Og + c * 8) = v;
    }
  };

  __syncthreads();
  if (wave >= 2) dumpAcc(oA, l_A);
  __syncthreads();
  if (wave < 2) combineTile(oA, l_A);
  __syncthreads();
  storeTile(qtA);
  if (wave >= 2) dumpAcc(oB, l_B);
  __syncthreads();
  if (wave < 2) combineTile(oB, l_B);
  __syncthreads();
  storeTile(qtB);
}

// ---------------- launch ----------------
extern "C" void kernel_launch(void* const* d_in, const int* in_sizes, int n_in,
                              void* d_out, int out_size, void* d_ws, size_t ws_size,
                              hipStream_t stream) {
  const float* x      = (const float*)d_in[0];
  const float* w_attn = (const float*)d_in[1];
  const float* b_attn = (const float*)d_in[2];
  const float* w_proj = (const float*)d_in[3];
  const float* b_proj = (const float*)d_in[4];
  float* out = (float*)d_out;

  char* p = (char*)d_ws;
  bf16_t* xb  = (bf16_t*)p; p += (size_t)4096 * 2048 * 2;      // x bf16 [B*T][C]
  bf16_t* waT = (bf16_t*)p; p += (size_t)6144 * 2048 * 2;      // w_attn^T bf16 [3C][C]
  bf16_t* wpT = (bf16_t*)p; p += (size_t)2048 * 2048 * 2;      // w_proj^T bf16 [C][C]
  bf16_t* Qb  = (bf16_t*)p; p += (size_t)32 * 2048 * 128 * 2;  // [B,H,T,hd] (pre-scaled)
  bf16_t* Kb  = (bf16_t*)p; p += (size_t)32 * 2048 * 128 * 2;  // [B,H,T,hd]
  bf16_t* Vb  = (bf16_t*)p; p += (size_t)32 * 2048 * 128 * 2;  // [B,H,hd,T] (transposed)
  bf16_t* Ob  = (bf16_t*)p; p += (size_t)4096 * 2048 * 2;      // attn out bf16 [B*T][C]

  cvt_f32_bf16<<<8192, 256, 0, stream>>>(x, xb, 2097152);
  transpose_cvt<<<dim3(6144 / 32, 2048 / 32), dim3(32, 8), 0, stream>>>(w_attn, waT, 2048, 6144);
  transpose_cvt<<<dim3(2048 / 32, 2048 / 32), dim3(32, 8), 0, stream>>>(w_proj, wpT, 2048, 2048);

  gemm_qkv<<<dim3(6144 / GBN, 4096 / GBM), 512, 0, stream>>>(
      xb, waT, b_attn, Qb, Kb, Vb, 2048);

  attn<<<dim3(16, 32), 256, 0, stream>>>(Qb, Kb, Vb, Ob);

  gemm_proj<<<dim3(2048 / TN, 4096 / TM), 256, 0, stream>>>(
      Ob, wpT, b_proj, out, 4096, 2048, 2048);
}

// Round 7
// 389.608 us; speedup vs baseline: 1.0583x; 1.0583x over previous
//
#include <hip/hip_runtime.h>
#include <cstdint>
#include <cstddef>

typedef __bf16 bf16_t;
typedef __bf16 bf16x8 __attribute__((ext_vector_type(8)));
typedef __bf16 bf16x4 __attribute__((ext_vector_type(4)));
typedef float floatx4 __attribute__((ext_vector_type(4)));
typedef float f32x16 __attribute__((ext_vector_type(16)));

#define B_  2
#define T_  2048
#define C_  2048
#define H_  16
#define HD_ 128

// 1/sqrt(128) * log2(e) — folded into Q at QKV-GEMM epilogue
#define K_ATTN_SCALE (0.08838834764831843f * 1.44269504088896f)

// ---- async global->LDS, 16B per lane (m97 recipe) ----
__device__ __forceinline__ void async_copy16(const void* g, void* l) {
  __builtin_amdgcn_global_load_lds((const __attribute__((address_space(1))) unsigned int*)g,
                                   (__attribute__((address_space(3))) unsigned int*)l,
                                   16, 0, 0);
}

#define BAR()     asm volatile("s_barrier" ::: "memory")
#define VMCNT(n)  asm volatile("s_waitcnt vmcnt(" #n ")" ::: "memory")

// ---------------- convert fp32 -> bf16 (flat) ----------------
__global__ __launch_bounds__(256) void cvt_f32_bf16(const float* __restrict__ in,
                                                    bf16_t* __restrict__ out, int n4) {
  int i = blockIdx.x * 256 + threadIdx.x;
  if (i >= n4) return;
  const float4 v = ((const float4*)in)[i];
  bf16x4 o;
  o[0] = (bf16_t)v.x; o[1] = (bf16_t)v.y; o[2] = (bf16_t)v.z; o[3] = (bf16_t)v.w;
  ((bf16x4*)out)[i] = o;
}

// ------- transpose + convert: W[Kd][Nd] fp32 -> Wt[Nd][Kd] bf16 -------
__global__ __launch_bounds__(256) void transpose_cvt(const float* __restrict__ W,
                                                     bf16_t* __restrict__ Wt,
                                                     int Kd, int Nd) {
  __shared__ float tile[32][33];
  const int tx = threadIdx.x, ty = threadIdx.y;
  const int n0 = blockIdx.x * 32, k0 = blockIdx.y * 32;
#pragma unroll
  for (int j = ty; j < 32; j += 8)
    tile[j][tx] = W[(size_t)(k0 + j) * Nd + n0 + tx];
  __syncthreads();
#pragma unroll
  for (int j = ty; j < 32; j += 8)
    Wt[(size_t)(n0 + j) * Kd + k0 + tx] = (bf16_t)tile[tx][j];
}

// =====================================================================
// GEMM — 256x128 tile, 8 waves (4M x 2N, wave tile 64x64), BK=64 as
// 2 k-slices of 32. Round-5 verified pipeline: register fragment dbuf,
// 2 phases/tile (16 MFMA each), 2 barriers/tile, counted vmcnt(3).
// Grid: QKV 48x16 = 768 wgs = 3 exact rounds; proj 16x16 = 256 = 1 round.
// LDS: 2 bufs x (A 32KB + B 16KB) = 96 KiB. 64B rows, slot ^= (r>>1)&3.
// Staging: P0(t) stages (t+1,k1); P1(t) stages (t+2,k0). Each staged
// region's prior readers complete (reg-dep lgkm before MFMA) >=1 barrier
// before the overwriting stage.
// MODE 0: QKV epilogue (Q/K scatter, V transpose via LDS). MODE 1: f32 C.
// =====================================================================
#define GBM 256
#define GBN 128
#define GBK 64

template <int MODE>
__global__ __launch_bounds__(512, 2) void gemm256(
    const bf16_t* __restrict__ A, const bf16_t* __restrict__ Bt,
    const float* __restrict__ bias, float* __restrict__ Cout,
    bf16_t* __restrict__ Qo, bf16_t* __restrict__ Ko, bf16_t* __restrict__ Vo,
    int N, int K) {
  __shared__ __align__(16) char smem[98304];
  const int tid = threadIdx.x;
  const int wave = tid >> 6, lane = tid & 63;
  const int quad = lane >> 4, l15 = lane & 15;
  const int wm = wave >> 1, wn = wave & 1;
  const int bm = blockIdx.y * GBM, bn = blockIdx.x * GBN;

  // ---- staging map: linear LDS dest <- inverse-swizzled global source ----
  // A slice 16KB: p = l*8192 + tid*16, row r = p>>6 (0..255);
  // B slice  8KB: p = tid*16,          row r = p>>6 (0..127);
  // phys 16B slot (p>>4)&3 holds logical slot ((p>>4)&3) ^ ((r>>1)&3).
  const bf16_t* asrc[2];
  const bf16_t* bsrc;
#pragma unroll
  for (int l = 0; l < 2; ++l) {
    int p = l * 8192 + tid * 16;
    int r = p >> 6;
    int c = ((p >> 4) & 3) ^ ((r >> 1) & 3);
    asrc[l] = A + (size_t)(bm + r) * K + c * 8;
  }
  {
    int p = tid * 16;
    int r = p >> 6;
    int c = ((p >> 4) & 3) ^ ((r >> 1) & 3);
    bsrc = Bt + (size_t)(bn + r) * K + c * 8;
  }

  // stage one k-slice (A 2 loads + B 1 load per thread)
  auto stage = [&](int buf, int ks, int kofs) {
    char* Asl = smem + buf * 49152 + ks * 16384;
    char* Bsl = smem + buf * 49152 + 32768 + ks * 8192;
    async_copy16(asrc[0] + kofs, Asl + tid * 16);
    async_copy16(asrc[1] + kofs, Asl + 8192 + tid * 16);
    async_copy16(bsrc + kofs, Bsl + tid * 16);
  };

  // ---- read-side addressing (identical scheme to verified round-5) ----
  const int sxr = ((l15 >> 1) & 3) << 4;
  const int cb  = (quad * 16) ^ sxr;
  const int arow = (wm * 64 + l15) * 64;   // + i*1024
  const int brow = (wn * 64 + l15) * 64;   // + j*1024

  floatx4 acc[4][4] = {};
  bf16x8 a0[4], a1[4], b0[4], b1[4];

  // ---- prologue: (0,k0),(0,k1),(1,k0) in flight; drain (0,*) ----
  stage(0, 0, 0);
  stage(0, 1, 32);
  stage(1, 0, GBK);
  VMCNT(3);
  BAR();
  {
    const char* Ab = smem;
    const char* Bb = smem + 32768;
#pragma unroll
    for (int i = 0; i < 4; ++i)
      a0[i] = *(const bf16x8*)(Ab + arow + i * 1024 + cb);
#pragma unroll
    for (int j = 0; j < 4; ++j)
      b0[j] = *(const bf16x8*)(Bb + brow + j * 1024 + cb);
  }

  const int NT = K / GBK;   // 32
  for (int t = 0; t < NT; ++t) {
    const char* Ab  = smem + (t & 1) * 49152;
    const char* Bb  = Ab + 32768;
    const char* Abn = smem + ((t + 1) & 1) * 49152;
    const char* Bbn = Abn + 32768;

    // -------- P0: MFMA(a0,b0); load (ks1) frags; stage (t+1,k1) --------
#pragma unroll
    for (int i = 0; i < 4; ++i)
      a1[i] = *(const bf16x8*)(Ab + 16384 + arow + i * 1024 + cb);
#pragma unroll
    for (int j = 0; j < 4; ++j)
      b1[j] = *(const bf16x8*)(Bb + 8192 + brow + j * 1024 + cb);
    if (t + 1 < NT) stage((t + 1) & 1, 1, (t + 1) * GBK + 32);
#pragma unroll
    for (int i = 0; i < 4; ++i)
#pragma unroll
      for (int j = 0; j < 4; ++j)
        acc[i][j] = __builtin_amdgcn_mfma_f32_16x16x32_bf16(a0[i], b0[j], acc[i][j], 0, 0, 0);
    if (t + 1 < NT) { VMCNT(3); }   // drain (t+1,k0); (t+1,k1) stays in flight
    BAR();

    // -------- P1: MFMA(a1,b1); load next-tile ks0 frags; stage (t+2,k0) --------
    if (t + 1 < NT) {
#pragma unroll
      for (int i = 0; i < 4; ++i)
        a0[i] = *(const bf16x8*)(Abn + arow + i * 1024 + cb);
#pragma unroll
      for (int j = 0; j < 4; ++j)
        b0[j] = *(const bf16x8*)(Bbn + brow + j * 1024 + cb);
    }
    if (t + 2 < NT) stage(t & 1, 0, (t + 2) * GBK);
#pragma unroll
    for (int i = 0; i < 4; ++i)
#pragma unroll
      for (int j = 0; j < 4; ++j)
        acc[i][j] = __builtin_amdgcn_mfma_f32_16x16x32_bf16(a1[i], b1[j], acc[i][j], 0, 0, 0);
    if (t + 2 < NT)      { VMCNT(3); }   // drain (t+1,k1); (t+2,k0) stays
    else if (t + 1 < NT) { VMCNT(0); }   // tail: drain (t+1,k1)
    BAR();
  }

  // ---------------- epilogue ----------------
  float bias_r[4];
#pragma unroll
  for (int j = 0; j < 4; ++j)
    bias_r[j] = bias[bn + wn * 64 + j * 16 + l15];

  if (MODE == 1) {
#pragma unroll
    for (int i = 0; i < 4; ++i) {
#pragma unroll
      for (int j = 0; j < 4; ++j) {
#pragma unroll
        for (int r = 0; r < 4; ++r) {
          int m = bm + wm * 64 + i * 16 + quad * 4 + r;
          int n = bn + wn * 64 + j * 16 + l15;
          Cout[(size_t)m * N + n] = acc[i][j][r] + bias_r[j];
        }
      }
    }
    return;
  }

  if (bn < 2 * C_) {
    // ---- Q / K scatter to [B,H,T,hd] ----
    const int which = bn >> 11;  // 0 = Q, 1 = K (uniform per block; 2048%128==0)
    bf16_t* dst0 = which ? Ko : Qo;
    const float scl = which ? 1.0f : K_ATTN_SCALE;
#pragma unroll
    for (int i = 0; i < 4; ++i) {
      const int m = bm + wm * 64 + i * 16 + quad * 4;
      const int b = m >> 11, tq = m & 2047;
#pragma unroll
      for (int j = 0; j < 4; ++j) {
        const int n = bn + wn * 64 + j * 16 + l15;
        const int cc = n & 2047;
        const int h = cc >> 7, d = cc & 127;
        bf16_t* dst = dst0 + (((size_t)(b * H_ + h)) * T_ + tq) * HD_ + d;
#pragma unroll
        for (int r = 0; r < 4; ++r)
          dst[(size_t)r * HD_] = (bf16_t)((acc[i][j][r] + bias_r[j]) * scl);
      }
    }
  } else {
    // ---- V block: transpose 256x128 tile through LDS (64 KiB of dead bufs) ----
    __syncthreads();  // all waves fully past main-loop LDS reads
    bf16_t* vt = (bf16_t*)smem;   // [128 d][256 t], 16B chunk ct ^= (d&31)
#pragma unroll
    for (int i = 0; i < 4; ++i) {
      const int tl0 = wm * 64 + i * 16 + quad * 4;
#pragma unroll
      for (int j = 0; j < 4; ++j) {
        const int dl = wn * 64 + j * 16 + l15;
        const int sw = dl & 31;
#pragma unroll
        for (int r = 0; r < 4; ++r) {
          const int tl = tl0 + r;
          vt[dl * 256 + ((((tl >> 3) ^ sw) << 3) + (tl & 7))] =
              (bf16_t)(acc[i][j][r] + bias_r[j]);
        }
      }
    }
    __syncthreads();
    const int d = tid >> 2, seg = tid & 3;
    const int h = (bn - 2 * C_) >> 7;
    const int b = bm >> 11, t0g = bm & 2047;
    bf16_t* dst = Vo + ((size_t)(b * H_ + h) * HD_ + d) * T_ + t0g;
#pragma unroll
    for (int c8 = 0; c8 < 8; ++c8) {
      const int chunk = seg * 8 + c8;
      uint4 v = *(const uint4*)&vt[d * 256 + ((chunk ^ (d & 31)) << 3)];
      *(uint4*)(dst + chunk * 8) = v;
    }
  }
}

// =====================================================================
// Causal flash attention — 32x32x16 MFMA, in-lane softmax (round-5 verified)
// =====================================================================
__global__ __launch_bounds__(256) void attn(const bf16_t* __restrict__ Q,
                                            const bf16_t* __restrict__ Kg,
                                            const bf16_t* __restrict__ Vt,
                                            bf16_t* __restrict__ O) {
  __shared__ __align__(16) char smem[66560];   // Ks 32K | Vs 32K | lbuf 1K
  const int tid = threadIdx.x;
  const int wave = tid >> 6, lane = tid & 63;
  const int hi = lane >> 5, l31 = lane & 31;
  const int qh = wave & 1, kh = wave >> 1;
  const int j = blockIdx.x;        // 0..15
  const int bh = blockIdx.y;
  const int b = bh >> 4, h = bh & 15;
  const int qtA = 31 - j, qtB = j;           // heavy, light
  const int nchA = qtA + 1, nchB = qtB + 1;

  const bf16_t* Qh = Q + (size_t)bh * T_ * HD_;
  const bf16_t* Kh = Kg + (size_t)bh * T_ * HD_;
  const bf16_t* Vh = Vt + (size_t)bh * HD_ * T_;

  float* xb32 = (float*)smem;                 // 32KB combine buffer (epilogue)
  float* lbuf = (float*)(smem + 65536);       // 512B l exchange

  auto stage = [&](int buf, int kt0) {
#pragma unroll
    for (int it = 0; it < 4; ++it) {
      int p = it * 4096 + tid * 16;
      int r = p >> 8;
      int cg = ((p >> 4) & 15) ^ (r & 15);
      async_copy16(Kh + (size_t)(kt0 + r) * HD_ + cg * 8, smem + buf * 16384 + p);
    }
#pragma unroll
    for (int it = 0; it < 4; ++it) {
      int p = it * 4096 + tid * 16;
      int r = p >> 7;
      int cg = ((p >> 4) & 7) ^ (r & 7);
      async_copy16(Vh + (size_t)r * T_ + kt0 + cg * 8, smem + 32768 + buf * 16384 + p);
    }
  };

  const int q0Arow = qtA * 64 + qh * 32;
  const int q0Brow = qtB * 64 + qh * 32;
  const bf16_t* qpA = Qh + (size_t)(q0Arow + l31) * HD_ + hi * 8;
  const bf16_t* qpB = Qh + (size_t)(q0Brow + l31) * HD_ + hi * 8;

  f32x16 oA[4] = {}, oB[4] = {};
  float l_A = 0.0f, l_B = 0.0f;

  const int swk = l31 & 15;
  const int swv = l31 & 7;
  const int krbase = (kh * 32 + l31) * 256;

  auto slot = [&](int buf, int kt0, const bf16_t* qp, f32x16 (&oacc)[4], float& l_i,
                  int qrow, bool mask) {
    const char* Kb = smem + buf * 16384;
    const char* Vb = smem + 32768 + buf * 16384;
    f32x16 s0 = {}, s1 = {};
#pragma unroll
    for (int m = 0; m < 4; ++m) {
      bf16x8 kf = *(const bf16x8*)(Kb + krbase + (((2 * m + hi) ^ swk) << 4));
      bf16x8 qf = *(const bf16x8*)(qp + m * 16);
      s0 = __builtin_amdgcn_mfma_f32_32x32x16_bf16(kf, qf, s0, 0, 0, 0);
    }
#pragma unroll
    for (int m = 4; m < 8; ++m) {
      bf16x8 kf = *(const bf16x8*)(Kb + krbase + (((2 * m + hi) ^ swk) << 4));
      bf16x8 qf = *(const bf16x8*)(qp + m * 16);
      s1 = __builtin_amdgcn_mfma_f32_32x32x16_bf16(kf, qf, s1, 0, 0, 0);
    }
    const int qg = qrow + l31;
    float p[16];
    float ps = 0.0f;
#pragma unroll
    for (int r = 0; r < 16; ++r) {
      float v = s0[r] + s1[r];
      float e = __builtin_amdgcn_exp2f(v);
      if (mask) {
        int kt = kt0 + kh * 32 + (r & 3) + 8 * (r >> 2) + 4 * hi;
        e = (kt <= qg) ? e : 0.0f;
      }
      ps += e;
      p[r] = e;
    }
    ps += __shfl_xor(ps, 32);
    l_i += ps;
    union PF { unsigned int w[4]; bf16x8 v; } pf[2];
#pragma unroll
    for (int m2 = 0; m2 < 2; ++m2) {
      union PK { bf16_t h[2]; unsigned int u; } a0, a1, c0, c1;
      const int ga = 8 * m2, gb = 8 * m2 + 4;
      a0.h[0] = (bf16_t)p[ga + 0]; a0.h[1] = (bf16_t)p[ga + 1];
      a1.h[0] = (bf16_t)p[ga + 2]; a1.h[1] = (bf16_t)p[ga + 3];
      c0.h[0] = (bf16_t)p[gb + 0]; c0.h[1] = (bf16_t)p[gb + 1];
      c1.h[0] = (bf16_t)p[gb + 2]; c1.h[1] = (bf16_t)p[gb + 3];
      unsigned int wa0 = a0.u, wa1 = a1.u, wb0 = c0.u, wb1 = c1.u;
      asm("v_permlane32_swap_b32 %0, %1" : "+v"(wa0), "+v"(wb0));
      asm("v_permlane32_swap_b32 %0, %1" : "+v"(wa1), "+v"(wb1));
      pf[m2].w[0] = wa0; pf[m2].w[1] = wa1; pf[m2].w[2] = wb0; pf[m2].w[3] = wb1;
    }
#pragma unroll
    for (int g = 0; g < 4; ++g) {
      const int vrb = (g * 32 + l31) * 128;
#pragma unroll
      for (int m2 = 0; m2 < 2; ++m2) {
        const int cc = kh * 4 + m2 * 2 + hi;
        bf16x8 vf = *(const bf16x8*)(Vb + vrb + ((cc ^ swv) << 4));
        oacc[g] = __builtin_amdgcn_mfma_f32_32x32x16_bf16(vf, pf[m2].v, oacc[g], 0, 0, 0);
      }
    }
  };

  stage(0, 0);
  for (int ch = 0; ch < nchA; ++ch) {
    __syncthreads();
    if (ch + 1 < nchA) stage((ch + 1) & 1, (ch + 1) * 64);
    const int buf = ch & 1;
    slot(buf, ch * 64, qpA, oA, l_A, q0Arow, ch == nchA - 1);
    if (ch < nchB)
      slot(buf, ch * 64, qpB, oB, l_B, q0Brow, ch == nchB - 1);
  }

  auto dumpAcc = [&](f32x16 (&o)[4], float lp) {
#pragma unroll
    for (int g = 0; g < 4; ++g)
#pragma unroll
      for (int r = 0; r < 16; ++r)
        xb32[qh * 4096 + (g * 16 + r) * 64 + lane] = o[g][r];
    lbuf[qh * 64 + lane] = lp;
  };
  auto combineTile = [&](f32x16 (&o)[4], float lp) {
    const float inv = 1.0f / (lp + lbuf[qh * 64 + lane]);
    const int rr = qh * 32 + l31;
    char* ob = smem + 32768 + rr * 256;
#pragma unroll
    for (int g = 0; g < 4; ++g)
#pragma unroll
      for (int r1 = 0; r1 < 4; ++r1) {
        union { bf16_t hh[4]; uint2 u2; } w;
#pragma unroll
        for (int k = 0; k < 4; ++k)
          w.hh[k] = (bf16_t)((o[g][r1 * 4 + k] +
                              xb32[qh * 4096 + (g * 16 + r1 * 4 + k) * 64 + lane]) * inv);
        const int chunk = 4 * g + r1;
        *(uint2*)(ob + ((chunk ^ (rr & 15)) << 4) + 8 * hi) = w.u2;
      }
  };
  auto storeTile = [&](int qt) {
    const int row = tid >> 2, seg = tid & 3;
    bf16_t* Og = O + ((size_t)(b * T_ + qt * 64 + row)) * C_ + h * HD_;
    const char* sb = smem + 32768 + row * 256;
#pragma unroll
    for (int c4 = 0; c4 < 4; ++c4) {
      const int c = seg * 4 + c4;
      uint4 v = *(const uint4*)(sb + ((c ^ (row & 15)) << 4));
      *(uint4*)(Og + c * 8) = v;
    }
  };

  __syncthreads();
  if (wave >= 2) dumpAcc(oA, l_A);
  __syncthreads();
  if (wave < 2) combineTile(oA, l_A);
  __syncthreads();
  storeTile(qtA);
  if (wave >= 2) dumpAcc(oB, l_B);
  __syncthreads();
  if (wave < 2) combineTile(oB, l_B);
  __syncthreads();
  storeTile(qtB);
}

// ---------------- launch ----------------
extern "C" void kernel_launch(void* const* d_in, const int* in_sizes, int n_in,
                              void* d_out, int out_size, void* d_ws, size_t ws_size,
                              hipStream_t stream) {
  const float* x      = (const float*)d_in[0];
  const float* w_attn = (const float*)d_in[1];
  const float* b_attn = (const float*)d_in[2];
  const float* w_proj = (const float*)d_in[3];
  const float* b_proj = (const float*)d_in[4];
  float* out = (float*)d_out;

  char* p = (char*)d_ws;
  bf16_t* xb  = (bf16_t*)p; p += (size_t)4096 * 2048 * 2;      // x bf16 [B*T][C]
  bf16_t* waT = (bf16_t*)p; p += (size_t)6144 * 2048 * 2;      // w_attn^T bf16 [3C][C]
  bf16_t* wpT = (bf16_t*)p; p += (size_t)2048 * 2048 * 2;      // w_proj^T bf16 [C][C]
  bf16_t* Qb  = (bf16_t*)p; p += (size_t)32 * 2048 * 128 * 2;  // [B,H,T,hd] (pre-scaled)
  bf16_t* Kb  = (bf16_t*)p; p += (size_t)32 * 2048 * 128 * 2;  // [B,H,T,hd]
  bf16_t* Vb  = (bf16_t*)p; p += (size_t)32 * 2048 * 128 * 2;  // [B,H,hd,T] (transposed)
  bf16_t* Ob  = (bf16_t*)p; p += (size_t)4096 * 2048 * 2;      // attn out bf16 [B*T][C]

  cvt_f32_bf16<<<8192, 256, 0, stream>>>(x, xb, 2097152);
  transpose_cvt<<<dim3(6144 / 32, 2048 / 32), dim3(32, 8), 0, stream>>>(w_attn, waT, 2048, 6144);
  transpose_cvt<<<dim3(2048 / 32, 2048 / 32), dim3(32, 8), 0, stream>>>(w_proj, wpT, 2048, 2048);

  gemm256<0><<<dim3(6144 / GBN, 4096 / GBM), 512, 0, stream>>>(
      xb, waT, b_attn, nullptr, Qb, Kb, Vb, 6144, 2048);

  attn<<<dim3(16, 32), 256, 0, stream>>>(Qb, Kb, Vb, Ob);

  gemm256<1><<<dim3(2048 / GBN, 4096 / GBM), 512, 0, stream>>>(
      Ob, wpT, b_proj, out, nullptr, nullptr, nullptr, 2048, 2048);
}